// Round 9
// baseline (112.120 us; speedup 1.0000x reference)
//
#include <hip/hip_runtime.h>
#include <hip/hip_bf16.h>

#define A_TOT 32
#define SEQ 1024
#define DIM 64

typedef __attribute__((ext_vector_type(8))) short short8;
typedef __attribute__((ext_vector_type(4))) float f32x4;

static __device__ __forceinline__ unsigned pack2bf(float a, float b) {
    union { __hip_bfloat16 h[2]; unsigned u; } x;
    x.h[0] = __float2bfloat16(a);
    x.h[1] = __float2bfloat16(b);
    return x.u;
}

// ---------------- cast fp32 -> bf16 ----------------
__global__ void cast_bf16_kernel(const float* __restrict__ src,
                                 __hip_bfloat16* __restrict__ dst, int n) {
    int i = (blockIdx.x * blockDim.x + threadIdx.x) * 4;
    if (i >= n) return;
    float4 f = *reinterpret_cast<const float4*>(src + i);
    union { __hip_bfloat16 h[4]; ushort4 u; } cv;
    cv.h[0] = __float2bfloat16(f.x);
    cv.h[1] = __float2bfloat16(f.y);
    cv.h[2] = __float2bfloat16(f.z);
    cv.h[3] = __float2bfloat16(f.w);
    *reinterpret_cast<ushort4*>(dst + i) = cv.u;
}

// ---------------- transpose+cast v [bh][n][d] -> vt [bh][d][n] ----------------
__global__ void transpose_v_kernel(const float* __restrict__ v,
                                   __hip_bfloat16* __restrict__ vt) {
    __shared__ __hip_bfloat16 tile[64][65];
    int bh = blockIdx.y;
    int n0 = blockIdx.x * 64;
    const float* vsrc = v + ((size_t)bh * SEQ + n0) * DIM;
    for (int e = threadIdx.x; e < 64 * 64; e += 256) {
        int i = e >> 6;
        int d = e & 63;
        tile[i][d] = __float2bfloat16(vsrc[(size_t)i * DIM + d]);
    }
    __syncthreads();
    __hip_bfloat16* vdst = vt + (size_t)bh * DIM * SEQ + n0;
    for (int e = threadIdx.x; e < 64 * 64; e += 256) {
        int d = e >> 6;
        int i = e & 63;
        vdst[(size_t)d * SEQ + i] = tile[i][d];
    }
}

// ---------------- fused masked attention, split-KV, K-permuted, fused QK+PV ----
// grid: (64 row-blocks of 16 rows, 32 bh), block 256 (4 waves).
// Wave w owns rows [rb*16,+16) x KV cols [w*256,+256).
// K rows loaded permuted so mfma(K,Q) output lands in PV A-fragment ownership.
// Round 9: QK and PV fused per tile (O accumulates UNNORMALIZED p; final
// scale by 1/l happens at the olds combine). launch_bounds(256,3) raises the
// VGPR cap to ~170 so the batched loads stay materialized (R8 got squeezed
// to 72 VGPRs and re-serialized).
__launch_bounds__(256, 3)
__global__ void graph_attn_kernel(const __hip_bfloat16* __restrict__ qb,
                                  const __hip_bfloat16* __restrict__ kb,
                                  const __hip_bfloat16* __restrict__ vt,
                                  const int* __restrict__ adj,
                                  float* __restrict__ out,    // [32,1024,64]
                                  float* __restrict__ attn) { // [32,1024,1024]
    __shared__ float olds[4][16][68];      // O partial combine (17408 B)
    __shared__ float part[4][4][16];       // per-wave per-lgi row partials
    __shared__ float lsum_sh[4][16];       // per-wave row sums

    const int bh    = blockIdx.y;
    const int rb    = blockIdx.x;
    const int batch = bh & 3;           // a_idx = h*4 + batch
    const int tid   = threadIdx.x;
    const int wid   = tid >> 6;
    const int lane  = tid & 63;
    const int lr    = lane & 15;        // query row within the 16-row tile
    const int lgi   = lane >> 4;        // k-group / reg-group
    const int row16 = rb * 16;
    const int kvbase = wid * 256;

    // Q fragments: lane holds Q[row16+lr][lgi*8 .. +8) per 32-wide k-step
    const __hip_bfloat16* qrow = qb + ((size_t)bh * SEQ + row16 + lr) * DIM + lgi * 8;
    const short8 qf0 = *reinterpret_cast<const short8*>(qrow);
    const short8 qf1 = *reinterpret_cast<const short8*>(qrow + 32);

    const int* adjrow = adj + (size_t)batch * SEQ * SEQ + (size_t)(row16 + lr) * SEQ;
    const __hip_bfloat16* kbh = kb + (size_t)bh * SEQ * DIM;

    // loader-role row permutation constant for this lane
    const int kperm = (lr >> 2) * 8 + (lr & 3);

    float lp = 0.f;         // lane partial sum of exp over its owned columns
    unsigned p_pk[4][4][2]; // packed unnormalized p: [t][c][pair]
    f32x4 o[4];             // UNNORMALIZED output accumulator
#pragma unroll
    for (int c = 0; c < 4; ++c) o[c] = (f32x4){0.f, 0.f, 0.f, 0.f};

    // ---- fused main loop: per tile t do QK^T -> exp -> PV ----
#pragma unroll
    for (int t = 0; t < 4; ++t) {
        const int n0 = kvbase + t * 64;
        // batch-issue K loads + adj loads + V loads for this tile
        short8 kf[4][2];
#pragma unroll
        for (int c = 0; c < 4; ++c) {
            const int colbase = (c >> 1) * 32 + (c & 1) * 4;
            const __hip_bfloat16* krow =
                kbh + (size_t)(n0 + colbase + kperm) * DIM + lgi * 8;
            kf[c][0] = *reinterpret_cast<const short8*>(krow);
            kf[c][1] = *reinterpret_cast<const short8*>(krow + 32);
        }
        int4 av4[4];
#pragma unroll
        for (int c = 0; c < 4; ++c) {
            const int colbase = (c >> 1) * 32 + (c & 1) * 4;
            av4[c] = *reinterpret_cast<const int4*>(adjrow + n0 + colbase + lgi * 8);
        }
        short8 vf[4][2];
#pragma unroll
        for (int c2 = 0; c2 < 4; ++c2) {
            const __hip_bfloat16* vrow =
                vt + ((size_t)bh * DIM + c2 * 16 + lr) * SEQ + n0 + lgi * 8;
            vf[c2][0] = *reinterpret_cast<const short8*>(vrow);
            vf[c2][1] = *reinterpret_cast<const short8*>(vrow + 32);
        }
        // QK^T compute: 4 x (2 MFMA + mask + exp + pack)
#pragma unroll
        for (int c = 0; c < 4; ++c) {
            f32x4 acc = {0.f, 0.f, 0.f, 0.f};
            acc = __builtin_amdgcn_mfma_f32_16x16x32_bf16(kf[c][0], qf0, acc, 0, 0, 0);
            acc = __builtin_amdgcn_mfma_f32_16x16x32_bf16(kf[c][1], qf1, acc, 0, 0, 0);
            // acc[j] = S[q=row16+lr][kv = n0 + colbase + lgi*8 + j]
            float p0 = (av4[c].x > 0) ? __expf(acc[0] * 0.125f) : 0.f;
            float p1 = (av4[c].y > 0) ? __expf(acc[1] * 0.125f) : 0.f;
            float p2 = (av4[c].z > 0) ? __expf(acc[2] * 0.125f) : 0.f;
            float p3 = (av4[c].w > 0) ? __expf(acc[3] * 0.125f) : 0.f;
            lp += (p0 + p1) + (p2 + p3);
            p_pk[t][c][0] = pack2bf(p0, p1);
            p_pk[t][c][1] = pack2bf(p2, p3);
        }
        // PV on unnormalized p (register-concat fragments)
        union { unsigned u[4]; short8 s; } pf0, pf1;
        pf0.u[0] = p_pk[t][0][0]; pf0.u[1] = p_pk[t][0][1];
        pf0.u[2] = p_pk[t][1][0]; pf0.u[3] = p_pk[t][1][1];
        pf1.u[0] = p_pk[t][2][0]; pf1.u[1] = p_pk[t][2][1];
        pf1.u[2] = p_pk[t][3][0]; pf1.u[3] = p_pk[t][3][1];
#pragma unroll
        for (int c2 = 0; c2 < 4; ++c2) {
            o[c2] = __builtin_amdgcn_mfma_f32_16x16x32_bf16(pf0.s, vf[c2][0], o[c2], 0, 0, 0);
            o[c2] = __builtin_amdgcn_mfma_f32_16x16x32_bf16(pf1.s, vf[c2][1], o[c2], 0, 0, 0);
        }
    }

    // ---- Phase B: wave-local row sums via LDS, then cross-wave combine ----
    part[wid][lgi][lr] = lp;
    asm volatile("" ::: "memory");
    if (lane < 16) {
        lsum_sh[wid][lane] = part[wid][0][lane] + part[wid][1][lane] +
                             part[wid][2][lane] + part[wid][3][lane];
    }
    __syncthreads();

    float ltot[4];
#pragma unroll
    for (int j = 0; j < 4; ++j) {
        const int row = lgi * 4 + j;
        float s = lsum_sh[0][row] + lsum_sh[1][row] + lsum_sh[2][row] + lsum_sh[3][row];
        ltot[j] = 1.0f / (s + 1e-37f);
    }
    float lrt = lsum_sh[0][lr] + lsum_sh[1][lr] + lsum_sh[2][lr] + lsum_sh[3][lr];
    const float linv_r = 1.0f / (lrt + 1e-37f);

    // ---- Phase D: attn writes (normalized, unpacked from regs) ----
    float* attn_row = attn + (size_t)bh * SEQ * SEQ + (size_t)(row16 + lr) * SEQ;
#pragma unroll
    for (int t = 0; t < 4; ++t) {
#pragma unroll
        for (int c = 0; c < 4; ++c) {
            const int colbase = (c >> 1) * 32 + (c & 1) * 4;
            const unsigned u01 = p_pk[t][c][0];
            const unsigned u23 = p_pk[t][c][1];
            float f0 = __uint_as_float(u01 << 16) * linv_r;
            float f1 = __uint_as_float(u01 & 0xffff0000u) * linv_r;
            float f2 = __uint_as_float(u23 << 16) * linv_r;
            float f3 = __uint_as_float(u23 & 0xffff0000u) * linv_r;
            *reinterpret_cast<float4*>(attn_row + kvbase + t * 64 + colbase + lgi * 8) =
                (float4){f0, f1, f2, f3};
        }
    }

    // ---- scale O partials by 1/l, combine across waves ----
#pragma unroll
    for (int c2 = 0; c2 < 4; ++c2)
#pragma unroll
        for (int j = 0; j < 4; ++j)
            olds[wid][lgi * 4 + j][c2 * 16 + lr] = o[c2][j] * ltot[j];
    __syncthreads();

    const int r  = tid >> 4;  // 0..15
    const int c4 = tid & 15;  // 0..15 (float4 column)
    float s0 = 0.f, s1 = 0.f, s2 = 0.f, s3 = 0.f;
#pragma unroll
    for (int w = 0; w < 4; ++w) {
        s0 += olds[w][r][c4 * 4 + 0];
        s1 += olds[w][r][c4 * 4 + 1];
        s2 += olds[w][r][c4 * 4 + 2];
        s3 += olds[w][r][c4 * 4 + 3];
    }
    float* ob = out + (size_t)bh * SEQ * DIM + (size_t)(row16 + r) * DIM + c4 * 4;
    *reinterpret_cast<float4*>(ob) = (float4){s0, s1, s2, s3};
}

extern "C" void kernel_launch(void* const* d_in, const int* in_sizes, int n_in,
                              void* d_out, int out_size, void* d_ws, size_t ws_size,
                              hipStream_t stream) {
    const float* q   = (const float*)d_in[0];
    const float* k   = (const float*)d_in[1];
    const float* v   = (const float*)d_in[2];
    const int*   adj = (const int*)d_in[3];

    float* out  = (float*)d_out;                   // [32,1024,64]
    float* attn = out + (size_t)A_TOT * SEQ * DIM; // [32,1024,1024]

    __hip_bfloat16* qb = (__hip_bfloat16*)d_ws;
    __hip_bfloat16* kb = qb + (size_t)A_TOT * SEQ * DIM;
    __hip_bfloat16* vt = kb + (size_t)A_TOT * SEQ * DIM;

    const int n = A_TOT * SEQ * DIM;  // 2,097,152
    cast_bf16_kernel<<<n / (4 * 256), 256, 0, stream>>>(q, qb, n);
    cast_bf16_kernel<<<n / (4 * 256), 256, 0, stream>>>(k, kb, n);
    transpose_v_kernel<<<dim3(SEQ / 64, A_TOT), 256, 0, stream>>>(v, vt);
    graph_attn_kernel<<<dim3(SEQ / 16, A_TOT), 256, 0, stream>>>(qb, kb, vt, adj, out, attn);
}

// Round 10
// 110.386 us; speedup vs baseline: 1.0157x; 1.0157x over previous
//
#include <hip/hip_runtime.h>
#include <hip/hip_bf16.h>

#define A_TOT 32
#define SEQ 1024
#define DIM 64

typedef __attribute__((ext_vector_type(8))) short short8;
typedef __attribute__((ext_vector_type(4))) float f32x4;
typedef __attribute__((ext_vector_type(4))) int i32x4;

static __device__ __forceinline__ unsigned pack2bf(float a, float b) {
    union { __hip_bfloat16 h[2]; unsigned u; } x;
    x.h[0] = __float2bfloat16(a);
    x.h[1] = __float2bfloat16(b);
    return x.u;
}

// Forced 16B global load: asm output must stay live in 4 VGPRs; the
// compiler cannot re-serialize or rematerialize it (R7-R9 failure mode).
static __device__ __forceinline__ i32x4 gload16(const void* p) {
    i32x4 r;
    asm volatile("global_load_dwordx4 %0, %1, off" : "=v"(r) : "v"(p));
    return r;
}
// Drain all outstanding vector loads. sched_barrier stops hipcc from
// hoisting register-only consumers above the wait (guide rule #18).
static __device__ __forceinline__ void wait_vm0() {
    asm volatile("s_waitcnt vmcnt(0)" ::: "memory");
    __builtin_amdgcn_sched_barrier(0);
}

// ---------------- cast fp32 -> bf16 ----------------
__global__ void cast_bf16_kernel(const float* __restrict__ src,
                                 __hip_bfloat16* __restrict__ dst, int n) {
    int i = (blockIdx.x * blockDim.x + threadIdx.x) * 4;
    if (i >= n) return;
    float4 f = *reinterpret_cast<const float4*>(src + i);
    union { __hip_bfloat16 h[4]; ushort4 u; } cv;
    cv.h[0] = __float2bfloat16(f.x);
    cv.h[1] = __float2bfloat16(f.y);
    cv.h[2] = __float2bfloat16(f.z);
    cv.h[3] = __float2bfloat16(f.w);
    *reinterpret_cast<ushort4*>(dst + i) = cv.u;
}

// ---------------- transpose+cast v [bh][n][d] -> vt [bh][d][n] ----------------
__global__ void transpose_v_kernel(const float* __restrict__ v,
                                   __hip_bfloat16* __restrict__ vt) {
    __shared__ __hip_bfloat16 tile[64][65];
    int bh = blockIdx.y;
    int n0 = blockIdx.x * 64;
    const float* vsrc = v + ((size_t)bh * SEQ + n0) * DIM;
    for (int e = threadIdx.x; e < 64 * 64; e += 256) {
        int i = e >> 6;
        int d = e & 63;
        tile[i][d] = __float2bfloat16(vsrc[(size_t)i * DIM + d]);
    }
    __syncthreads();
    __hip_bfloat16* vdst = vt + (size_t)bh * DIM * SEQ + n0;
    for (int e = threadIdx.x; e < 64 * 64; e += 256) {
        int d = e >> 6;
        int i = e & 63;
        vdst[(size_t)d * SEQ + i] = tile[i][d];
    }
}

// ---------------- fused masked attention, split-KV, K-permuted, asm-batched ----
// grid: (64 row-blocks of 16 rows, 32 bh), block 256 (4 waves).
// Wave w owns rows [rb*16,+16) x KV cols [w*256,+256).
// K rows loaded permuted so mfma(K,Q) output lands in PV A-fragment ownership.
// Round 10: all 20 loads of a tile issued via inline-asm global_load_dwordx4
// (un-re-serializable), single vmcnt(0) drain per tile, then register-only
// compute. O accumulates unnormalized; scaled at the olds combine.
__launch_bounds__(256)
__global__ void graph_attn_kernel(const __hip_bfloat16* __restrict__ qb,
                                  const __hip_bfloat16* __restrict__ kb,
                                  const __hip_bfloat16* __restrict__ vt,
                                  const int* __restrict__ adj,
                                  float* __restrict__ out,    // [32,1024,64]
                                  float* __restrict__ attn) { // [32,1024,1024]
    __shared__ float olds[4][16][68];      // O partial combine (17408 B)
    __shared__ float part[4][4][16];       // per-wave per-lgi row partials
    __shared__ float lsum_sh[4][16];       // per-wave row sums

    const int bh    = blockIdx.y;
    const int rb    = blockIdx.x;
    const int batch = bh & 3;           // a_idx = h*4 + batch
    const int tid   = threadIdx.x;
    const int wid   = tid >> 6;
    const int lane  = tid & 63;
    const int lr    = lane & 15;        // query row within the 16-row tile
    const int lgi   = lane >> 4;        // k-group / reg-group
    const int row16 = rb * 16;
    const int kvbase = wid * 256;

    // Q fragments: lane holds Q[row16+lr][lgi*8 .. +8) per 32-wide k-step
    const __hip_bfloat16* qrow = qb + ((size_t)bh * SEQ + row16 + lr) * DIM + lgi * 8;
    const short8 qf0 = *reinterpret_cast<const short8*>(qrow);
    const short8 qf1 = *reinterpret_cast<const short8*>(qrow + 32);

    const int* adjrow = adj + (size_t)batch * SEQ * SEQ + (size_t)(row16 + lr) * SEQ;
    const __hip_bfloat16* kbh = kb + (size_t)bh * SEQ * DIM;

    // loader-role row permutation constant for this lane
    const int kperm = (lr >> 2) * 8 + (lr & 3);

    float lp = 0.f;         // lane partial sum of exp over its owned columns
    unsigned p_pk[4][4][2]; // packed unnormalized p: [t][c][pair]
    f32x4 o[4];             // UNNORMALIZED output accumulator
#pragma unroll
    for (int c = 0; c < 4; ++c) o[c] = (f32x4){0.f, 0.f, 0.f, 0.f};

    // ---- fused main loop: per tile t: asm-batch 20 loads, drain, compute ----
#pragma unroll
    for (int t = 0; t < 4; ++t) {
        const int n0 = kvbase + t * 64;
        i32x4 kraw[4][2];
#pragma unroll
        for (int c = 0; c < 4; ++c) {
            const int colbase = (c >> 1) * 32 + (c & 1) * 4;
            const __hip_bfloat16* krow =
                kbh + (size_t)(n0 + colbase + kperm) * DIM + lgi * 8;
            kraw[c][0] = gload16(krow);
            kraw[c][1] = gload16(krow + 32);
        }
        i32x4 araw[4];
#pragma unroll
        for (int c = 0; c < 4; ++c) {
            const int colbase = (c >> 1) * 32 + (c & 1) * 4;
            araw[c] = gload16(adjrow + n0 + colbase + lgi * 8);
        }
        i32x4 vraw[4][2];
#pragma unroll
        for (int c2 = 0; c2 < 4; ++c2) {
            const __hip_bfloat16* vrow =
                vt + ((size_t)bh * DIM + c2 * 16 + lr) * SEQ + n0 + lgi * 8;
            vraw[c2][0] = gload16(vrow);
            vraw[c2][1] = gload16(vrow + 32);
        }
        wait_vm0();  // one drain for all 20 loads of this tile

        // QK^T compute: 4 x (2 MFMA + mask + exp + pack)
#pragma unroll
        for (int c = 0; c < 4; ++c) {
            f32x4 acc = {0.f, 0.f, 0.f, 0.f};
            acc = __builtin_amdgcn_mfma_f32_16x16x32_bf16(
                __builtin_bit_cast(short8, kraw[c][0]), qf0, acc, 0, 0, 0);
            acc = __builtin_amdgcn_mfma_f32_16x16x32_bf16(
                __builtin_bit_cast(short8, kraw[c][1]), qf1, acc, 0, 0, 0);
            // acc[j] = S[q=row16+lr][kv = n0 + colbase + lgi*8 + j]
            float p0 = (araw[c][0] > 0) ? __expf(acc[0] * 0.125f) : 0.f;
            float p1 = (araw[c][1] > 0) ? __expf(acc[1] * 0.125f) : 0.f;
            float p2 = (araw[c][2] > 0) ? __expf(acc[2] * 0.125f) : 0.f;
            float p3 = (araw[c][3] > 0) ? __expf(acc[3] * 0.125f) : 0.f;
            lp += (p0 + p1) + (p2 + p3);
            p_pk[t][c][0] = pack2bf(p0, p1);
            p_pk[t][c][1] = pack2bf(p2, p3);
        }
        // PV on unnormalized p (register-concat fragments)
        union { unsigned u[4]; short8 s; } pf0, pf1;
        pf0.u[0] = p_pk[t][0][0]; pf0.u[1] = p_pk[t][0][1];
        pf0.u[2] = p_pk[t][1][0]; pf0.u[3] = p_pk[t][1][1];
        pf1.u[0] = p_pk[t][2][0]; pf1.u[1] = p_pk[t][2][1];
        pf1.u[2] = p_pk[t][3][0]; pf1.u[3] = p_pk[t][3][1];
#pragma unroll
        for (int c2 = 0; c2 < 4; ++c2) {
            o[c2] = __builtin_amdgcn_mfma_f32_16x16x32_bf16(
                pf0.s, __builtin_bit_cast(short8, vraw[c2][0]), o[c2], 0, 0, 0);
            o[c2] = __builtin_amdgcn_mfma_f32_16x16x32_bf16(
                pf1.s, __builtin_bit_cast(short8, vraw[c2][1]), o[c2], 0, 0, 0);
        }
    }

    // ---- Phase B: wave-local row sums via LDS, then cross-wave combine ----
    part[wid][lgi][lr] = lp;
    asm volatile("" ::: "memory");
    if (lane < 16) {
        lsum_sh[wid][lane] = part[wid][0][lane] + part[wid][1][lane] +
                             part[wid][2][lane] + part[wid][3][lane];
    }
    __syncthreads();

    float ltot[4];
#pragma unroll
    for (int j = 0; j < 4; ++j) {
        const int row = lgi * 4 + j;
        float s = lsum_sh[0][row] + lsum_sh[1][row] + lsum_sh[2][row] + lsum_sh[3][row];
        ltot[j] = 1.0f / (s + 1e-37f);
    }
    float lrt = lsum_sh[0][lr] + lsum_sh[1][lr] + lsum_sh[2][lr] + lsum_sh[3][lr];
    const float linv_r = 1.0f / (lrt + 1e-37f);

    // ---- Phase D: attn writes (normalized, unpacked from regs) ----
    float* attn_row = attn + (size_t)bh * SEQ * SEQ + (size_t)(row16 + lr) * SEQ;
#pragma unroll
    for (int t = 0; t < 4; ++t) {
#pragma unroll
        for (int c = 0; c < 4; ++c) {
            const int colbase = (c >> 1) * 32 + (c & 1) * 4;
            const unsigned u01 = p_pk[t][c][0];
            const unsigned u23 = p_pk[t][c][1];
            float f0 = __uint_as_float(u01 << 16) * linv_r;
            float f1 = __uint_as_float(u01 & 0xffff0000u) * linv_r;
            float f2 = __uint_as_float(u23 << 16) * linv_r;
            float f3 = __uint_as_float(u23 & 0xffff0000u) * linv_r;
            *reinterpret_cast<float4*>(attn_row + kvbase + t * 64 + colbase + lgi * 8) =
                (float4){f0, f1, f2, f3};
        }
    }

    // ---- scale O partials by 1/l, combine across waves ----
#pragma unroll
    for (int c2 = 0; c2 < 4; ++c2)
#pragma unroll
        for (int j = 0; j < 4; ++j)
            olds[wid][lgi * 4 + j][c2 * 16 + lr] = o[c2][j] * ltot[j];
    __syncthreads();

    const int r  = tid >> 4;  // 0..15
    const int c4 = tid & 15;  // 0..15 (float4 column)
    float s0 = 0.f, s1 = 0.f, s2 = 0.f, s3 = 0.f;
#pragma unroll
    for (int w = 0; w < 4; ++w) {
        s0 += olds[w][r][c4 * 4 + 0];
        s1 += olds[w][r][c4 * 4 + 1];
        s2 += olds[w][r][c4 * 4 + 2];
        s3 += olds[w][r][c4 * 4 + 3];
    }
    float* ob = out + (size_t)bh * SEQ * DIM + (size_t)(row16 + r) * DIM + c4 * 4;
    *reinterpret_cast<float4*>(ob) = (float4){s0, s1, s2, s3};
}

extern "C" void kernel_launch(void* const* d_in, const int* in_sizes, int n_in,
                              void* d_out, int out_size, void* d_ws, size_t ws_size,
                              hipStream_t stream) {
    const float* q   = (const float*)d_in[0];
    const float* k   = (const float*)d_in[1];
    const float* v   = (const float*)d_in[2];
    const int*   adj = (const int*)d_in[3];

    float* out  = (float*)d_out;                   // [32,1024,64]
    float* attn = out + (size_t)A_TOT * SEQ * DIM; // [32,1024,1024]

    __hip_bfloat16* qb = (__hip_bfloat16*)d_ws;
    __hip_bfloat16* kb = qb + (size_t)A_TOT * SEQ * DIM;
    __hip_bfloat16* vt = kb + (size_t)A_TOT * SEQ * DIM;

    const int n = A_TOT * SEQ * DIM;  // 2,097,152
    cast_bf16_kernel<<<n / (4 * 256), 256, 0, stream>>>(q, qb, n);
    cast_bf16_kernel<<<n / (4 * 256), 256, 0, stream>>>(k, kb, n);
    transpose_v_kernel<<<dim3(SEQ / 64, A_TOT), 256, 0, stream>>>(v, vt);
    graph_attn_kernel<<<dim3(SEQ / 16, A_TOT), 256, 0, stream>>>(qb, kb, vt, adj, out, attn);
}

// Round 11
// 79.108 us; speedup vs baseline: 1.4173x; 1.3954x over previous
//
#include <hip/hip_runtime.h>
#include <hip/hip_bf16.h>

#define A_TOT 32
#define SEQ 1024
#define DIM 64
#define NT 16          // KV tiles of 64
#define GSTRIDE 1056   // 8-row group stride (1024B data + 32B pad)
#define TILEB (8 * GSTRIDE)

typedef __attribute__((ext_vector_type(8))) short short8;
typedef __attribute__((ext_vector_type(4))) float f32x4;

static __device__ __forceinline__ unsigned pack2bf(float a, float b) {
    union { __hip_bfloat16 h[2]; unsigned u; } x;
    x.h[0] = __float2bfloat16(a);
    x.h[1] = __float2bfloat16(b);
    return x.u;
}

// async 16B/lane global->LDS (dest = uniform base + lane*16, linear)
static __device__ __forceinline__ void gload_lds16(const void* g, void* l) {
    __builtin_amdgcn_global_load_lds(
        (const __attribute__((address_space(1))) unsigned*)g,
        (__attribute__((address_space(3))) unsigned*)l, 16, 0, 0);
}

// swizzled 16B fragment read: tile-local row, global chunk (8 bf16)
static __device__ __forceinline__ short8 lds_frag(const unsigned char* tile,
                                                  int row, int chunk) {
    const int byte = (row >> 3) * GSTRIDE + (row & 7) * 128 +
                     ((chunk ^ (row & 7)) << 4);
    return *reinterpret_cast<const short8*>(tile + byte);
}

// ---------------- cast fp32 -> bf16 ----------------
__global__ void cast_bf16_kernel(const float* __restrict__ src,
                                 __hip_bfloat16* __restrict__ dst, int n) {
    int i = (blockIdx.x * blockDim.x + threadIdx.x) * 4;
    if (i >= n) return;
    float4 f = *reinterpret_cast<const float4*>(src + i);
    union { __hip_bfloat16 h[4]; ushort4 u; } cv;
    cv.h[0] = __float2bfloat16(f.x);
    cv.h[1] = __float2bfloat16(f.y);
    cv.h[2] = __float2bfloat16(f.z);
    cv.h[3] = __float2bfloat16(f.w);
    *reinterpret_cast<ushort4*>(dst + i) = cv.u;
}

// ---------------- transpose+cast v [bh][n][d] -> vt [bh][d][n] ----------------
__global__ void transpose_v_kernel(const float* __restrict__ v,
                                   __hip_bfloat16* __restrict__ vt) {
    __shared__ __hip_bfloat16 tile[64][65];
    int bh = blockIdx.y;
    int n0 = blockIdx.x * 64;
    const float* vsrc = v + ((size_t)bh * SEQ + n0) * DIM;
    for (int e = threadIdx.x; e < 64 * 64; e += 256) {
        int i = e >> 6;
        int d = e & 63;
        tile[i][d] = __float2bfloat16(vsrc[(size_t)i * DIM + d]);
    }
    __syncthreads();
    __hip_bfloat16* vdst = vt + (size_t)bh * DIM * SEQ + n0;
    for (int e = threadIdx.x; e < 64 * 64; e += 256) {
        int d = e >> 6;
        int i = e & 63;
        vdst[(size_t)d * SEQ + i] = tile[i][d];
    }
}

// ---------------- fused masked attention: LDS-staged 2-phase pipeline ----------
// grid: (16 row-blocks of 64 rows, 32 bh), block 256 (4 waves x 16 rows).
// Each wave: 16 query rows x full KV (16 tiles of 64). K/V tiles staged
// cooperatively via global_load_lds (8-row groups, 1056B stride, XOR-chunk
// swizzle; linear dest + pre-swizzled source + swizzled read). Two sweeps:
// A = row sums l (K only), B = normalized attn + PV (K+V). One barrier per
// tile; attn stores issued post-barrier; adj prefetched one tile ahead.
__launch_bounds__(256)
__global__ void graph_attn_kernel(const __hip_bfloat16* __restrict__ qb,
                                  const __hip_bfloat16* __restrict__ kb,
                                  const __hip_bfloat16* __restrict__ vt,
                                  const int* __restrict__ adj,
                                  float* __restrict__ out,    // [32,1024,64]
                                  float* __restrict__ attn) { // [32,1024,1024]
    __shared__ __align__(16) unsigned char kstage[2][TILEB];
    __shared__ __align__(16) unsigned char vstage[2][TILEB];
    __shared__ float part[4][4][16];
    __shared__ float lsum_sh[4][16];

    const int bh    = blockIdx.y;
    const int rb    = blockIdx.x;
    const int batch = bh & 3;
    const int tid   = threadIdx.x;
    const int wid   = tid >> 6;
    const int lane  = tid & 63;
    const int lr    = lane & 15;
    const int lgi   = lane >> 4;
    const int row16 = rb * 64 + wid * 16;

    // staging lane constants: 8 rows x 8 chunks per instruction
    const int sub  = lane >> 3;          // row within 8-row group
    const int csrc = (lane & 7) ^ sub;   // pre-swizzled source chunk

    const __hip_bfloat16* qrow = qb + ((size_t)bh * SEQ + row16 + lr) * DIM + lgi * 8;
    const short8 qf0 = *reinterpret_cast<const short8*>(qrow);
    const short8 qf1 = *reinterpret_cast<const short8*>(qrow + 32);

    const int* adjrow = adj + (size_t)batch * SEQ * SEQ + (size_t)(row16 + lr) * SEQ;
    const __hip_bfloat16* kbh = kb + (size_t)bh * SEQ * DIM;
    const __hip_bfloat16* vth = vt + (size_t)bh * DIM * SEQ;

    const int kperm = (lr >> 2) * 8 + (lr & 3);  // validated R7 row permutation

    // --- staging helpers (per wave: 2 instr K, 2 instr V per tile) ---
    auto stageK = [&](int t, int b) {
        const __hip_bfloat16* g0 = kbh + (size_t)(t * 64 + wid * 16) * DIM;
        unsigned char* l0 = &kstage[b][(wid * 2) * GSTRIDE];
        gload_lds16(g0 + (size_t)sub * DIM + csrc * 8, l0);
        gload_lds16(g0 + (size_t)(8 + sub) * DIM + csrc * 8, l0 + GSTRIDE);
    };
    auto stageV = [&](int t, int b) {
        const __hip_bfloat16* g0 = vth + (size_t)(wid * 16) * SEQ + t * 64;
        unsigned char* l0 = &vstage[b][(wid * 2) * GSTRIDE];
        gload_lds16(g0 + (size_t)sub * SEQ + csrc * 8, l0);
        gload_lds16(g0 + (size_t)(8 + sub) * SEQ + csrc * 8, l0 + GSTRIDE);
    };

    // ================= sweep A: row sums =================
    float lp = 0.f;
    int4 avb[4], avn[4];
#pragma unroll
    for (int c = 0; c < 4; ++c) {
        const int cb = (c >> 1) * 32 + (c & 1) * 4;
        avb[c] = *reinterpret_cast<const int4*>(adjrow + cb + lgi * 8);
    }
    stageK(0, 0);
    __syncthreads();

    int cur = 0;
    for (int t = 0; t < NT; ++t) {
        if (t < NT - 1) {
            stageK(t + 1, cur ^ 1);
#pragma unroll
            for (int c = 0; c < 4; ++c) {
                const int cb = (c >> 1) * 32 + (c & 1) * 4;
                avn[c] = *reinterpret_cast<const int4*>(
                    adjrow + (t + 1) * 64 + cb + lgi * 8);
            }
        }
#pragma unroll
        for (int c = 0; c < 4; ++c) {
            const int cb = (c >> 1) * 32 + (c & 1) * 4;
            const int krow = cb + kperm;
            short8 kf0 = lds_frag(kstage[cur], krow, lgi);
            short8 kf1 = lds_frag(kstage[cur], krow, 4 + lgi);
            f32x4 acc = {0.f, 0.f, 0.f, 0.f};
            acc = __builtin_amdgcn_mfma_f32_16x16x32_bf16(kf0, qf0, acc, 0, 0, 0);
            acc = __builtin_amdgcn_mfma_f32_16x16x32_bf16(kf1, qf1, acc, 0, 0, 0);
            float p0 = (avb[c].x > 0) ? __expf(acc[0] * 0.125f) : 0.f;
            float p1 = (avb[c].y > 0) ? __expf(acc[1] * 0.125f) : 0.f;
            float p2 = (avb[c].z > 0) ? __expf(acc[2] * 0.125f) : 0.f;
            float p3 = (avb[c].w > 0) ? __expf(acc[3] * 0.125f) : 0.f;
            lp += (p0 + p1) + (p2 + p3);
        }
        __syncthreads();  // implicit vmcnt(0): staging for t+1 landed
#pragma unroll
        for (int c = 0; c < 4; ++c) avb[c] = avn[c];
        cur ^= 1;
    }

    // wave-local row sums (validated LDS pattern, wave-internal, no barrier)
    part[wid][lgi][lr] = lp;
    asm volatile("" ::: "memory");
    float lsum4 = 0.f;
    if (lane < 16) {
        lsum4 = part[wid][0][lane] + part[wid][1][lane] +
                part[wid][2][lane] + part[wid][3][lane];
        lsum_sh[wid][lane] = lsum4;
    }
    asm volatile("" ::: "memory");
    const float linv = 1.0f / (lsum_sh[wid][lr] + 1e-37f);

    // ================= sweep B: attn + PV =================
    f32x4 o[4];
#pragma unroll
    for (int c = 0; c < 4; ++c) o[c] = (f32x4){0.f, 0.f, 0.f, 0.f};

#pragma unroll
    for (int c = 0; c < 4; ++c) {
        const int cb = (c >> 1) * 32 + (c & 1) * 4;
        avb[c] = *reinterpret_cast<const int4*>(adjrow + cb + lgi * 8);
    }
    stageK(0, 0);
    stageV(0, 0);
    __syncthreads();

    float* attn_row = attn + (size_t)bh * SEQ * SEQ + (size_t)(row16 + lr) * SEQ;
    cur = 0;
    for (int t = 0; t < NT; ++t) {
        if (t < NT - 1) {
            stageK(t + 1, cur ^ 1);
            stageV(t + 1, cur ^ 1);
#pragma unroll
            for (int c = 0; c < 4; ++c) {
                const int cb = (c >> 1) * 32 + (c & 1) * 4;
                avn[c] = *reinterpret_cast<const int4*>(
                    adjrow + (t + 1) * 64 + cb + lgi * 8);
            }
        }
        unsigned pk[4][2];
#pragma unroll
        for (int c = 0; c < 4; ++c) {
            const int cb = (c >> 1) * 32 + (c & 1) * 4;
            const int krow = cb + kperm;
            short8 kf0 = lds_frag(kstage[cur], krow, lgi);
            short8 kf1 = lds_frag(kstage[cur], krow, 4 + lgi);
            f32x4 acc = {0.f, 0.f, 0.f, 0.f};
            acc = __builtin_amdgcn_mfma_f32_16x16x32_bf16(kf0, qf0, acc, 0, 0, 0);
            acc = __builtin_amdgcn_mfma_f32_16x16x32_bf16(kf1, qf1, acc, 0, 0, 0);
            // acc[j] = S[row16+lr][t*64 + cb + lgi*8 + j]; normalize directly
            float p0 = (avb[c].x > 0) ? __expf(acc[0] * 0.125f) * linv : 0.f;
            float p1 = (avb[c].y > 0) ? __expf(acc[1] * 0.125f) * linv : 0.f;
            float p2 = (avb[c].z > 0) ? __expf(acc[2] * 0.125f) * linv : 0.f;
            float p3 = (avb[c].w > 0) ? __expf(acc[3] * 0.125f) * linv : 0.f;
            pk[c][0] = pack2bf(p0, p1);
            pk[c][1] = pack2bf(p2, p3);
        }
        // PV: A-fragments are register concats (validated R7 mapping)
        union { unsigned u[4]; short8 s; } pf0, pf1;
        pf0.u[0] = pk[0][0]; pf0.u[1] = pk[0][1];
        pf0.u[2] = pk[1][0]; pf0.u[3] = pk[1][1];
        pf1.u[0] = pk[2][0]; pf1.u[1] = pk[2][1];
        pf1.u[2] = pk[3][0]; pf1.u[3] = pk[3][1];
#pragma unroll
        for (int c2 = 0; c2 < 4; ++c2) {
            const int vrow = c2 * 16 + lr;
            short8 vf0 = lds_frag(vstage[cur], vrow, lgi);
            short8 vf1 = lds_frag(vstage[cur], vrow, 4 + lgi);
            o[c2] = __builtin_amdgcn_mfma_f32_16x16x32_bf16(pf0.s, vf0, o[c2], 0, 0, 0);
            o[c2] = __builtin_amdgcn_mfma_f32_16x16x32_bf16(pf1.s, vf1, o[c2], 0, 0, 0);
        }
        __syncthreads();  // implicit vmcnt(0): next tile staged; prev stores drained
        // attn stores post-barrier: fly during next tile's stage+compute
#pragma unroll
        for (int c = 0; c < 4; ++c) {
            const int cb = (c >> 1) * 32 + (c & 1) * 4;
            const unsigned u01 = pk[c][0];
            const unsigned u23 = pk[c][1];
            float f0 = __uint_as_float(u01 << 16);
            float f1 = __uint_as_float(u01 & 0xffff0000u);
            float f2 = __uint_as_float(u23 << 16);
            float f3 = __uint_as_float(u23 & 0xffff0000u);
            *reinterpret_cast<float4*>(attn_row + t * 64 + cb + lgi * 8) =
                (float4){f0, f1, f2, f3};
        }
#pragma unroll
        for (int c = 0; c < 4; ++c) avb[c] = avn[c];
        cur ^= 1;
    }

    // ---- O epilogue: already normalized; direct coalesced-ish stores ----
    float* ob = out + (size_t)bh * SEQ * DIM + (size_t)row16 * DIM;
#pragma unroll
    for (int c2 = 0; c2 < 4; ++c2)
#pragma unroll
        for (int j = 0; j < 4; ++j)
            ob[(size_t)(lgi * 4 + j) * DIM + c2 * 16 + lr] = o[c2][j];
}

extern "C" void kernel_launch(void* const* d_in, const int* in_sizes, int n_in,
                              void* d_out, int out_size, void* d_ws, size_t ws_size,
                              hipStream_t stream) {
    const float* q   = (const float*)d_in[0];
    const float* k   = (const float*)d_in[1];
    const float* v   = (const float*)d_in[2];
    const int*   adj = (const int*)d_in[3];

    float* out  = (float*)d_out;                   // [32,1024,64]
    float* attn = out + (size_t)A_TOT * SEQ * DIM; // [32,1024,1024]

    __hip_bfloat16* qb = (__hip_bfloat16*)d_ws;
    __hip_bfloat16* kb = qb + (size_t)A_TOT * SEQ * DIM;
    __hip_bfloat16* vt = kb + (size_t)A_TOT * SEQ * DIM;

    const int n = A_TOT * SEQ * DIM;  // 2,097,152
    cast_bf16_kernel<<<n / (4 * 256), 256, 0, stream>>>(q, qb, n);
    cast_bf16_kernel<<<n / (4 * 256), 256, 0, stream>>>(k, kb, n);
    transpose_v_kernel<<<dim3(SEQ / 64, A_TOT), 256, 0, stream>>>(v, vt);
    graph_attn_kernel<<<dim3(SEQ / 64, A_TOT), 256, 0, stream>>>(qb, kb, vt, adj, out, attn);
}